// Round 10
// baseline (822.415 us; speedup 1.0000x reference)
//
#include <hip/hip_runtime.h>
#include <math.h>

#define N_NODES 30000
#define N_EDGES 480000
#define HEADS   6
#define NN2 (2 * N_NODES)
#define NE2 (2 * N_EDGES)

typedef __attribute__((ext_vector_type(8))) short bf16x8;
typedef __attribute__((ext_vector_type(4))) float f32x4;
typedef __attribute__((ext_vector_type(2))) float f32x2;

// ---------- bf16 helpers ----------
__device__ __forceinline__ unsigned short f2bf(float f) {
    unsigned u = __float_as_uint(f);
    u += 0x7fffu + ((u >> 16) & 1u);   // RNE
    return (unsigned short)(u >> 16);
}
__device__ __forceinline__ float bf_lo(unsigned p) { return __uint_as_float(p << 16); }
__device__ __forceinline__ float bf_hi(unsigned p) { return __uint_as_float(p & 0xffff0000u); }

// ---------- layer-1 GEMM (K=11): VALU, both graphs batched ----------
template <int K, int HF, int TM>
__global__ void gemm1_kernel(const float* __restrict__ x0, const float* __restrict__ x1,
                             const float* __restrict__ W, unsigned short* __restrict__ z) {
    __shared__ float hs[TM * K];
    const int m0 = blockIdx.x * TM;
    const float* h = (m0 < N_NODES) ? (x0 + (size_t)m0 * K)
                                    : (x1 + (size_t)(m0 - N_NODES) * K);
    const int j = blockIdx.y * 64 + threadIdx.x;
    for (int idx = threadIdx.x; idx < TM * K; idx += 64) hs[idx] = h[idx];
    __syncthreads();
    if (j >= HF) return;
    float acc[TM];
#pragma unroll
    for (int m = 0; m < TM; ++m) acc[m] = 0.f;
    for (int k = 0; k < K; ++k) {
        float w = W[k * HF + j];
#pragma unroll
        for (int m = 0; m < TM; ++m) acc[m] = fmaf(hs[m * K + k], w, acc[m]);
    }
#pragma unroll
    for (int m = 0; m < TM; ++m) z[(size_t)(m0 + m) * HF + j] = f2bf(acc[m]);
}

// ---------- W -> Wt (transposed, bf16) ----------
__global__ void convert_wt_kernel(const float* __restrict__ W, unsigned short* __restrict__ Wt,
                                  int K, int HF) {
    const int idx = blockIdx.x * 256 + threadIdx.x;
    if (idx >= K * HF) return;
    const int k = idx / HF;
    const int n = idx - k * HF;
    Wt[n * K + k] = f2bf(W[idx]);
}

// ---------- MFMA GEMM over 2N rows ----------
template <int K, int HF>
__global__ __launch_bounds__(256) void gemm_mfma_kernel(
        const unsigned short* __restrict__ hbf, const unsigned short* __restrict__ Wt,
        unsigned short* __restrict__ z) {
    constexpr int KSTEPS = K / 32;
    const int wid = blockIdx.x * 4 + (threadIdx.x >> 6);
    if (wid >= NN2 / 16) return;
    const int lane = threadIdx.x & 63;
    const int r16  = lane & 15;
    const int quad = lane >> 4;
    const int m0 = wid * 16;

    bf16x8 afrag[KSTEPS];
    const unsigned short* ap = hbf + (size_t)(m0 + r16) * K + quad * 8;
#pragma unroll
    for (int i = 0; i < KSTEPS; ++i) afrag[i] = *(const bf16x8*)(ap + i * 32);

    const unsigned short* bp = Wt + (size_t)r16 * K + quad * 8;
    for (int t = 0; t < HF / 16; ++t) {
        f32x4 acc = {0.f, 0.f, 0.f, 0.f};
        const unsigned short* bpt = bp + (size_t)t * 16 * K;
#pragma unroll
        for (int i = 0; i < KSTEPS; ++i) {
            const bf16x8 bfrag = *(const bf16x8*)(bpt + i * 32);
            acc = __builtin_amdgcn_mfma_f32_16x16x32_bf16(afrag[i], bfrag, acc, 0, 0, 0);
        }
        // C/D layout: col = r16 (n), row = quad*4 + reg (m)
        unsigned short* zp = z + (size_t)(m0 + quad * 4) * HF + t * 16 + r16;
#pragma unroll
        for (int r = 0; r < 4; ++r) zp[(size_t)r * HF] = f2bf(acc[r]);
    }
}

// ---------- prep: es/ed per (node, head) from bf16 z + emit packed fp8 z copy ----------
template <int HF>
__global__ void prep_fp8_kernel(const unsigned short* __restrict__ z,
                                const float* __restrict__ a_s, const float* __restrict__ a_d,
                                float* __restrict__ es, float* __restrict__ ed,
                                unsigned* __restrict__ zf8) {
    constexpr int Fo = HF / HEADS;
    const int idx = blockIdx.x * 256 + threadIdx.x;
    if (idx >= NN2 * HEADS) return;
    const int n = idx / HEADS;
    const int h = idx - n * HEADS;
    const unsigned* zp = (const unsigned*)(z + (size_t)n * HF + h * Fo);
    unsigned* qp = zf8 + ((size_t)n * (HF / 4) + h * (Fo / 4));
    const float* as = a_s + h * Fo;
    const float* ad = a_d + h * Fo;
    float s = 0.f, d = 0.f;
#pragma unroll 4
    for (int q = 0; q < Fo / 4; ++q) {
        const unsigned za = zp[2 * q], zb = zp[2 * q + 1];
        const float f0 = bf_lo(za), f1 = bf_hi(za), f2 = bf_lo(zb), f3 = bf_hi(zb);
        s = fmaf(f0, as[4 * q], s);
        s = fmaf(f1, as[4 * q + 1], s);
        s = fmaf(f2, as[4 * q + 2], s);
        s = fmaf(f3, as[4 * q + 3], s);
        d = fmaf(f0, ad[4 * q], d);
        d = fmaf(f1, ad[4 * q + 1], d);
        d = fmaf(f2, ad[4 * q + 2], d);
        d = fmaf(f3, ad[4 * q + 3], d);
        int u = __builtin_amdgcn_cvt_pk_fp8_f32(f0, f1, 0, false);
        u = __builtin_amdgcn_cvt_pk_fp8_f32(f2, f3, u, true);
        qp[q] = (unsigned)u;
    }
    es[idx] = s;
    ed[idx] = d;
}

// ---------- CSR build (both graphs, global node ids) ----------
__global__ void zero_int_kernel(int* __restrict__ p, int n) {
    const int i = blockIdx.x * 256 + threadIdx.x;
    if (i < n) p[i] = 0;
}

__global__ void hist2_kernel(const int* __restrict__ ei0, const int* __restrict__ ei1,
                             int* __restrict__ cnt) {
    const int e = blockIdx.x * 256 + threadIdx.x;
    if (e >= NE2) return;
    const int g = e >= N_EDGES;
    const int* ei = g ? ei1 : ei0;
    const int e2 = e - g * N_EDGES;
    atomicAdd(&cnt[g * N_NODES + ei[N_EDGES + e2]], 1);
}

#define SCAN_NB ((NN2 + 1023) / 1024)
__global__ void scan1_kernel(const int* __restrict__ cnt, int* __restrict__ part,
                             int* __restrict__ bsum) {
    __shared__ int s[1024];
    const int t = threadIdx.x;
    const int gid = blockIdx.x * 1024 + t;
    const int v = (gid < NN2) ? cnt[gid] : 0;
    s[t] = v;
    __syncthreads();
    for (int d = 1; d < 1024; d <<= 1) {
        int x = (t >= d) ? s[t - d] : 0;
        __syncthreads();
        s[t] += x;
        __syncthreads();
    }
    part[gid] = s[t] - v;
    if (t == 1023) bsum[blockIdx.x] = s[1023];
}

__global__ void scan2_kernel(int* __restrict__ bsum, int* __restrict__ boff) {
    if (threadIdx.x == 0) {
        int a = 0;
        for (int i = 0; i < SCAN_NB; ++i) { boff[i] = a; a += bsum[i]; }
        boff[SCAN_NB] = a;
    }
}

__global__ void scan3_kernel(const int* __restrict__ part, const int* __restrict__ boff,
                             int* __restrict__ off, int* __restrict__ cursor) {
    const int gid = blockIdx.x * 1024 + threadIdx.x;
    if (gid < NN2) {
        const int o = part[gid] + boff[gid >> 10];
        off[gid] = o;
        cursor[gid] = o;
    }
    if (gid == 0) off[NN2] = boff[SCAN_NB];
}

__global__ void scatter2_kernel(const int* __restrict__ ei0, const int* __restrict__ ei1,
                                int* __restrict__ cursor, int* __restrict__ csr_src,
                                int* __restrict__ csr_dst) {
    const int e = blockIdx.x * 256 + threadIdx.x;
    if (e >= NE2) return;
    const int g = e >= N_EDGES;
    const int* ei = g ? ei1 : ei0;
    const int e2 = e - g * N_EDGES;
    const int src = g * N_NODES + ei[e2];
    const int dst = g * N_NODES + ei[N_EDGES + e2];
    const int slot = atomicAdd(&cursor[dst], 1);
    csr_src[slot] = src;
    csr_dst[slot] = dst;
}

// ---------- edge records: ew[h][slot] = {src:u16 | bf16(exp(leaky(es+ed)))<<16} ----------
// one thread per CSR slot; src < 60000 fits u16; one dword carries src AND weight
__global__ void edge_w_kernel(const int* __restrict__ csr_src, const int* __restrict__ csr_dst,
                              const float* __restrict__ es, const float* __restrict__ ed,
                              unsigned* __restrict__ ew) {
    const int slot = blockIdx.x * 256 + threadIdx.x;
    if (slot >= NE2) return;
    const int src = csr_src[slot];
    const int dst = csr_dst[slot];
#pragma unroll
    for (int h = 0; h < HEADS; ++h) {
        float v = es[src * HEADS + h] + ed[dst * HEADS + h];
        v = v > 0.f ? v : 0.2f * v;
        const float w = __expf(v);
        ew[(size_t)h * NE2 + slot] = (unsigned)src | ((unsigned)f2bf(w) << 16);
    }
}

// ---------- aggregation (layers 1-2): packed edge rec + fp8 gather + ELU, bf16 out ----
template <int HF>
__global__ void agg_fp8_kernel(const int* __restrict__ off, const unsigned* __restrict__ ew,
                               const unsigned* __restrict__ zf8,
                               unsigned short* __restrict__ outz) {
    constexpr int Fo  = HF / HEADS;
    constexpr int L   = Fo / 4;
    constexpr int EPI = 64 / L;
    const int wid  = (blockIdx.x * blockDim.x + threadIdx.x) >> 6;
    const int lane = threadIdx.x & 63;
    if (wid >= NN2 * HEADS) return;
    const int n = wid / HEADS;
    const int h = wid - n * HEADS;
    const int s0  = off[n];
    const int deg = off[n + 1] - s0;
    const int eo = lane / L;
    const int fp = lane - eo * L;
    const unsigned* ewh = ew + (size_t)h * NE2;

    float a0 = 0.f, a1 = 0.f, a2 = 0.f, a3 = 0.f, lsum = 0.f;
#pragma unroll 4
    for (int i = eo; i < deg; i += EPI) {
        const unsigned rec = ewh[s0 + i];        // one dword: src | w
        const int   src = rec & 0xffffu;
        const float ww  = bf_hi(rec);
        lsum += ww;
        const unsigned zz = zf8[(size_t)src * (HF / 4) + h * (Fo / 4) + fp];
        const f32x2 lo = __builtin_amdgcn_cvt_pk_f32_fp8((int)zz, false);
        const f32x2 hi = __builtin_amdgcn_cvt_pk_f32_fp8((int)zz, true);
        a0 = fmaf(ww, lo.x, a0);
        a1 = fmaf(ww, lo.y, a1);
        a2 = fmaf(ww, hi.x, a2);
        a3 = fmaf(ww, hi.y, a3);
    }
#pragma unroll
    for (int d = L; d < 64; d <<= 1) {
        a0 += __shfl_xor(a0, d);
        a1 += __shfl_xor(a1, d);
        a2 += __shfl_xor(a2, d);
        a3 += __shfl_xor(a3, d);
        lsum += __shfl_xor(lsum, d);
    }
    if (eo == 0) {
        const float inv = 1.f / (lsum + 1e-16f);
        float o0 = a0 * inv, o1 = a1 * inv, o2 = a2 * inv, o3 = a3 * inv;
        o0 = o0 > 0.f ? o0 : expm1f(o0);
        o1 = o1 > 0.f ? o1 : expm1f(o1);
        o2 = o2 > 0.f ? o2 : expm1f(o2);
        o3 = o3 > 0.f ? o3 : expm1f(o3);
        unsigned short* op = outz + (size_t)n * HF + h * Fo + 4 * fp;
        *(unsigned*)op       = (unsigned)f2bf(o0) | ((unsigned)f2bf(o1) << 16);
        *(unsigned*)(op + 2) = (unsigned)f2bf(o2) | ((unsigned)f2bf(o3) << 16);
    }
}

// ---------- layer-3 aggregation fused with sum pooling (hierarchical reduction) ----------
#define POOL_BPH 512
#define POOL_WPH (POOL_BPH * 4)   // waves per head = 2048
__global__ __launch_bounds__(256) void agg_pool_kernel(
        const int* __restrict__ off, const unsigned* __restrict__ ew,
        const unsigned* __restrict__ zf8, float* __restrict__ pooled) {
    constexpr int HF = 384, Fo = 64, L = 16, EPI = 4;
    __shared__ float lds[128];   // [graph][64 feats] for this block's head
    const int h     = blockIdx.x % HEADS;           // fixed head per BLOCK
    const int bslot = blockIdx.x / HEADS;
    const int wavid = threadIdx.x >> 6;
    const int ws    = bslot * 4 + wavid;
    const int lane  = threadIdx.x & 63;
    const int eo = lane / L;
    const int fp = lane - eo * L;
    const unsigned* ewh = ew + (size_t)h * NE2;

    if (threadIdx.x < 128) lds[threadIdx.x] = 0.f;
    __syncthreads();

    float p0[4] = {0.f, 0.f, 0.f, 0.f};
    float p1[4] = {0.f, 0.f, 0.f, 0.f};
    for (int n = ws; n < NN2; n += POOL_WPH) {
        const int s0  = off[n];
        const int deg = off[n + 1] - s0;
        float a0 = 0.f, a1 = 0.f, a2 = 0.f, a3 = 0.f, lsum = 0.f;
#pragma unroll 4
        for (int i = eo; i < deg; i += EPI) {
            const unsigned rec = ewh[s0 + i];
            const int   src = rec & 0xffffu;
            const float ww  = bf_hi(rec);
            lsum += ww;
            const unsigned zz = zf8[(size_t)src * (HF / 4) + h * (Fo / 4) + fp];
            const f32x2 lo = __builtin_amdgcn_cvt_pk_f32_fp8((int)zz, false);
            const f32x2 hi = __builtin_amdgcn_cvt_pk_f32_fp8((int)zz, true);
            a0 = fmaf(ww, lo.x, a0);
            a1 = fmaf(ww, lo.y, a1);
            a2 = fmaf(ww, hi.x, a2);
            a3 = fmaf(ww, hi.y, a3);
        }
#pragma unroll
        for (int d = L; d < 64; d <<= 1) {
            a0 += __shfl_xor(a0, d);
            a1 += __shfl_xor(a1, d);
            a2 += __shfl_xor(a2, d);
            a3 += __shfl_xor(a3, d);
            lsum += __shfl_xor(lsum, d);
        }
        if (eo == 0) {
            const float inv = 1.f / (lsum + 1e-16f);
            float o0 = a0 * inv, o1 = a1 * inv, o2 = a2 * inv, o3 = a3 * inv;
            o0 = o0 > 0.f ? o0 : expm1f(o0);
            o1 = o1 > 0.f ? o1 : expm1f(o1);
            o2 = o2 > 0.f ? o2 : expm1f(o2);
            o3 = o3 > 0.f ? o3 : expm1f(o3);
            if (n < N_NODES) { p0[0] += o0; p0[1] += o1; p0[2] += o2; p0[3] += o3; }
            else             { p1[0] += o0; p1[1] += o1; p1[2] += o2; p1[3] += o3; }
        }
    }
    if (eo == 0) {
#pragma unroll
        for (int j = 0; j < 4; ++j) {
            atomicAdd(&lds[4 * fp + j], p0[j]);
            atomicAdd(&lds[64 + 4 * fp + j], p1[j]);
        }
    }
    __syncthreads();
    if (threadIdx.x < 128) {
        const int g = threadIdx.x >> 6;
        const int f = threadIdx.x & 63;
        atomicAdd(&pooled[g * 384 + h * Fo + f], lds[threadIdx.x]);
    }
}

__global__ void zero_pooled_kernel(float* __restrict__ p) {
    const int i = blockIdx.x * 256 + threadIdx.x;
    if (i < 768) p[i] = 0.f;
}

__global__ void final_kernel(const float* __restrict__ pooled, const float* __restrict__ Wd,
                             const float* __restrict__ bd, float* __restrict__ outp) {
    __shared__ float s_ss[256], s_dot[256];
    const int t = threadIdx.x;
    float ss = 0.f, dot = 0.f;
    for (int c = t; c < 768; c += 256) {
        const float v = pooled[c];
        ss  = fmaf(v, v, ss);
        dot = fmaf(v, Wd[c], dot);
    }
    s_ss[t] = ss; s_dot[t] = dot;
    __syncthreads();
    for (int off = 128; off > 0; off >>= 1) {
        if (t < off) { s_ss[t] += s_ss[t + off]; s_dot[t] += s_dot[t + off]; }
        __syncthreads();
    }
    if (t == 0) {
        const float norm = fmaxf(sqrtf(s_ss[0]), 1e-12f);
        outp[0] = s_dot[0] / norm + bd[0];
    }
}

extern "C" void kernel_launch(void* const* d_in, const int* in_sizes, int n_in,
                              void* d_out, int out_size, void* d_ws, size_t ws_size,
                              hipStream_t stream) {
    const float* x_int = (const float*)d_in[0];
    const float* x_nh  = (const float*)d_in[1];
    const int*   ei_int = (const int*)d_in[2];
    const int*   ei_nh  = (const int*)d_in[3];
    const float* W1  = (const float*)d_in[4];
    const float* a1s = (const float*)d_in[5];
    const float* a1d = (const float*)d_in[6];
    const float* W2  = (const float*)d_in[7];
    const float* a2s = (const float*)d_in[8];
    const float* a2d = (const float*)d_in[9];
    const float* W3  = (const float*)d_in[10];
    const float* a3s = (const float*)d_in[11];
    const float* a3d = (const float*)d_in[12];
    const float* Wd  = (const float*)d_in[13];
    const float* bd  = (const float*)d_in[14];
    float* out = (float*)d_out;

    // workspace layout (zbuf 256B-aligned at base; all offsets keep 16B alignment)
    unsigned short* zbuf  = (unsigned short*)d_ws;                 // NN2*384 bf16
    unsigned short* hbf_a = zbuf  + (size_t)NN2 * 384;             // NN2*96
    unsigned short* hbf_b = hbf_a + (size_t)NN2 * 96;              // NN2*192
    unsigned short* wt2   = hbf_b + (size_t)NN2 * 192;             // 192*96
    unsigned short* wt3   = wt2   + (size_t)96 * 192;              // 384*192
    unsigned* zf8 = (unsigned*)(wt3 + (size_t)192 * 384);          // NN2*96 dwords (fp8)
    float* es    = (float*)(zf8 + (size_t)NN2 * 96);               // NN2*H
    float* ed    = es + (size_t)NN2 * HEADS;                       // NN2*H
    unsigned* ewbuf = (unsigned*)(ed + (size_t)NN2 * HEADS);       // H*NE2 packed {src,w}
    float* pooled = (float*)(ewbuf + (size_t)HEADS * NE2);         // 768
    int* cnt     = (int*)(pooled + 768);                           // NN2
    int* part    = cnt + NN2;                                      // SCAN_NB*1024
    int* bsum    = part + SCAN_NB * 1024;                          // SCAN_NB
    int* boff    = bsum + SCAN_NB;                                 // SCAN_NB+1
    int* off     = boff + SCAN_NB + 1;                             // NN2+1
    int* cursor  = off + NN2 + 1;                                  // NN2
    int* csr_src = cursor + NN2;                                   // NE2
    int* csr_dst = csr_src + NE2;                                  // NE2

    zero_pooled_kernel<<<3, 256, 0, stream>>>(pooled);
    convert_wt_kernel<<<(96 * 192 + 255) / 256, 256, 0, stream>>>(W2, wt2, 96, 192);
    convert_wt_kernel<<<(192 * 384 + 255) / 256, 256, 0, stream>>>(W3, wt3, 192, 384);

    // batched CSR over both graphs
    zero_int_kernel<<<(NN2 + 255) / 256, 256, 0, stream>>>(cnt, NN2);
    hist2_kernel<<<(NE2 + 255) / 256, 256, 0, stream>>>(ei_int, ei_nh, cnt);
    scan1_kernel<<<SCAN_NB, 1024, 0, stream>>>(cnt, part, bsum);
    scan2_kernel<<<1, 64, 0, stream>>>(bsum, boff);
    scan3_kernel<<<SCAN_NB, 1024, 0, stream>>>(part, boff, off, cursor);
    scatter2_kernel<<<(NE2 + 255) / 256, 256, 0, stream>>>(ei_int, ei_nh, cursor, csr_src,
                                                           csr_dst);

    const int mfma_blocks = (NN2 / 16 + 3) / 4;
    const int agg_blocks  = (NN2 * HEADS + 3) / 4;   // 1 wave per (node, head)
    const int prep_blocks = (NN2 * HEADS + 255) / 256;
    const int ew_blocks   = (NE2 + 255) / 256;

    // layer 1
    gemm1_kernel<11, 96, 16><<<dim3(NN2 / 16, 2), 64, 0, stream>>>(x_int, x_nh, W1, zbuf);
    prep_fp8_kernel<96><<<prep_blocks, 256, 0, stream>>>(zbuf, a1s, a1d, es, ed, zf8);
    edge_w_kernel<<<ew_blocks, 256, 0, stream>>>(csr_src, csr_dst, es, ed, ewbuf);
    agg_fp8_kernel<96><<<agg_blocks, 256, 0, stream>>>(off, ewbuf, zf8, hbf_a);
    // layer 2
    gemm_mfma_kernel<96, 192><<<mfma_blocks, 256, 0, stream>>>(hbf_a, wt2, zbuf);
    prep_fp8_kernel<192><<<prep_blocks, 256, 0, stream>>>(zbuf, a2s, a2d, es, ed, zf8);
    edge_w_kernel<<<ew_blocks, 256, 0, stream>>>(csr_src, csr_dst, es, ed, ewbuf);
    agg_fp8_kernel<192><<<agg_blocks, 256, 0, stream>>>(off, ewbuf, zf8, hbf_b);
    // layer 3 (+ fused pooling, hierarchical reduction)
    gemm_mfma_kernel<192, 384><<<mfma_blocks, 256, 0, stream>>>(hbf_b, wt3, zbuf);
    prep_fp8_kernel<384><<<prep_blocks, 256, 0, stream>>>(zbuf, a3s, a3d, es, ed, zf8);
    edge_w_kernel<<<ew_blocks, 256, 0, stream>>>(csr_src, csr_dst, es, ed, ewbuf);
    agg_pool_kernel<<<HEADS * POOL_BPH, 256, 0, stream>>>(off, ewbuf, zf8, pooled);

    final_kernel<<<1, 256, 0, stream>>>(pooled, Wd, bd, out);
}

// Round 11
// 780.350 us; speedup vs baseline: 1.0539x; 1.0539x over previous
//
#include <hip/hip_runtime.h>
#include <math.h>

#define N_NODES 30000
#define N_EDGES 480000
#define HEADS   6
#define NN2 (2 * N_NODES)
#define NE2 (2 * N_EDGES)

typedef __attribute__((ext_vector_type(8))) short bf16x8;
typedef __attribute__((ext_vector_type(4))) float f32x4;
typedef __attribute__((ext_vector_type(2))) float f32x2;

// ---------- bf16 helpers ----------
__device__ __forceinline__ unsigned short f2bf(float f) {
    unsigned u = __float_as_uint(f);
    u += 0x7fffu + ((u >> 16) & 1u);   // RNE
    return (unsigned short)(u >> 16);
}
__device__ __forceinline__ float bf_lo(unsigned p) { return __uint_as_float(p << 16); }
__device__ __forceinline__ float bf_hi(unsigned p) { return __uint_as_float(p & 0xffff0000u); }

// ---------- layer-1 GEMM (K=11): VALU, both graphs batched ----------
template <int K, int HF, int TM>
__global__ void gemm1_kernel(const float* __restrict__ x0, const float* __restrict__ x1,
                             const float* __restrict__ W, unsigned short* __restrict__ z) {
    __shared__ float hs[TM * K];
    const int m0 = blockIdx.x * TM;
    const float* h = (m0 < N_NODES) ? (x0 + (size_t)m0 * K)
                                    : (x1 + (size_t)(m0 - N_NODES) * K);
    const int j = blockIdx.y * 64 + threadIdx.x;
    for (int idx = threadIdx.x; idx < TM * K; idx += 64) hs[idx] = h[idx];
    __syncthreads();
    if (j >= HF) return;
    float acc[TM];
#pragma unroll
    for (int m = 0; m < TM; ++m) acc[m] = 0.f;
    for (int k = 0; k < K; ++k) {
        float w = W[k * HF + j];
#pragma unroll
        for (int m = 0; m < TM; ++m) acc[m] = fmaf(hs[m * K + k], w, acc[m]);
    }
#pragma unroll
    for (int m = 0; m < TM; ++m) z[(size_t)(m0 + m) * HF + j] = f2bf(acc[m]);
}

// ---------- W -> Wt (transposed, bf16) ----------
__global__ void convert_wt_kernel(const float* __restrict__ W, unsigned short* __restrict__ Wt,
                                  int K, int HF) {
    const int idx = blockIdx.x * 256 + threadIdx.x;
    if (idx >= K * HF) return;
    const int k = idx / HF;
    const int n = idx - k * HF;
    Wt[n * K + k] = f2bf(W[idx]);
}

// ---------- MFMA GEMM over 2N rows ----------
template <int K, int HF>
__global__ __launch_bounds__(256) void gemm_mfma_kernel(
        const unsigned short* __restrict__ hbf, const unsigned short* __restrict__ Wt,
        unsigned short* __restrict__ z) {
    constexpr int KSTEPS = K / 32;
    const int wid = blockIdx.x * 4 + (threadIdx.x >> 6);
    if (wid >= NN2 / 16) return;
    const int lane = threadIdx.x & 63;
    const int r16  = lane & 15;
    const int quad = lane >> 4;
    const int m0 = wid * 16;

    bf16x8 afrag[KSTEPS];
    const unsigned short* ap = hbf + (size_t)(m0 + r16) * K + quad * 8;
#pragma unroll
    for (int i = 0; i < KSTEPS; ++i) afrag[i] = *(const bf16x8*)(ap + i * 32);

    const unsigned short* bp = Wt + (size_t)r16 * K + quad * 8;
    for (int t = 0; t < HF / 16; ++t) {
        f32x4 acc = {0.f, 0.f, 0.f, 0.f};
        const unsigned short* bpt = bp + (size_t)t * 16 * K;
#pragma unroll
        for (int i = 0; i < KSTEPS; ++i) {
            const bf16x8 bfrag = *(const bf16x8*)(bpt + i * 32);
            acc = __builtin_amdgcn_mfma_f32_16x16x32_bf16(afrag[i], bfrag, acc, 0, 0, 0);
        }
        // C/D layout: col = r16 (n), row = quad*4 + reg (m)
        unsigned short* zp = z + (size_t)(m0 + quad * 4) * HF + t * 16 + r16;
#pragma unroll
        for (int r = 0; r < 4; ++r) zp[(size_t)r * HF] = f2bf(acc[r]);
    }
}

// ---------- prep: es/ed per (node, head) from bf16 z + emit packed fp8 z copy ----------
template <int HF>
__global__ void prep_fp8_kernel(const unsigned short* __restrict__ z,
                                const float* __restrict__ a_s, const float* __restrict__ a_d,
                                float* __restrict__ es, float* __restrict__ ed,
                                unsigned* __restrict__ zf8) {
    constexpr int Fo = HF / HEADS;
    const int idx = blockIdx.x * 256 + threadIdx.x;
    if (idx >= NN2 * HEADS) return;
    const int n = idx / HEADS;
    const int h = idx - n * HEADS;
    const unsigned* zp = (const unsigned*)(z + (size_t)n * HF + h * Fo);
    unsigned* qp = zf8 + ((size_t)n * (HF / 4) + h * (Fo / 4));
    const float* as = a_s + h * Fo;
    const float* ad = a_d + h * Fo;
    float s = 0.f, d = 0.f;
#pragma unroll 4
    for (int q = 0; q < Fo / 4; ++q) {
        const unsigned za = zp[2 * q], zb = zp[2 * q + 1];
        const float f0 = bf_lo(za), f1 = bf_hi(za), f2 = bf_lo(zb), f3 = bf_hi(zb);
        s = fmaf(f0, as[4 * q], s);
        s = fmaf(f1, as[4 * q + 1], s);
        s = fmaf(f2, as[4 * q + 2], s);
        s = fmaf(f3, as[4 * q + 3], s);
        d = fmaf(f0, ad[4 * q], d);
        d = fmaf(f1, ad[4 * q + 1], d);
        d = fmaf(f2, ad[4 * q + 2], d);
        d = fmaf(f3, ad[4 * q + 3], d);
        int u = __builtin_amdgcn_cvt_pk_fp8_f32(f0, f1, 0, false);
        u = __builtin_amdgcn_cvt_pk_fp8_f32(f2, f3, u, true);
        qp[q] = (unsigned)u;
    }
    es[idx] = s;
    ed[idx] = d;
}

// ---------- CSR build (both graphs, global node ids; src stored as u16) ----------
__global__ void zero_int_kernel(int* __restrict__ p, int n) {
    const int i = blockIdx.x * 256 + threadIdx.x;
    if (i < n) p[i] = 0;
}

__global__ void hist2_kernel(const int* __restrict__ ei0, const int* __restrict__ ei1,
                             int* __restrict__ cnt) {
    const int e = blockIdx.x * 256 + threadIdx.x;
    if (e >= NE2) return;
    const int g = e >= N_EDGES;
    const int* ei = g ? ei1 : ei0;
    const int e2 = e - g * N_EDGES;
    atomicAdd(&cnt[g * N_NODES + ei[N_EDGES + e2]], 1);
}

#define SCAN_NB ((NN2 + 1023) / 1024)
__global__ void scan1_kernel(const int* __restrict__ cnt, int* __restrict__ part,
                             int* __restrict__ bsum) {
    __shared__ int s[1024];
    const int t = threadIdx.x;
    const int gid = blockIdx.x * 1024 + t;
    const int v = (gid < NN2) ? cnt[gid] : 0;
    s[t] = v;
    __syncthreads();
    for (int d = 1; d < 1024; d <<= 1) {
        int x = (t >= d) ? s[t - d] : 0;
        __syncthreads();
        s[t] += x;
        __syncthreads();
    }
    part[gid] = s[t] - v;
    if (t == 1023) bsum[blockIdx.x] = s[1023];
}

__global__ void scan2_kernel(int* __restrict__ bsum, int* __restrict__ boff) {
    if (threadIdx.x == 0) {
        int a = 0;
        for (int i = 0; i < SCAN_NB; ++i) { boff[i] = a; a += bsum[i]; }
        boff[SCAN_NB] = a;
    }
}

__global__ void scan3_kernel(const int* __restrict__ part, const int* __restrict__ boff,
                             int* __restrict__ off, int* __restrict__ cursor) {
    const int gid = blockIdx.x * 1024 + threadIdx.x;
    if (gid < NN2) {
        const int o = part[gid] + boff[gid >> 10];
        off[gid] = o;
        cursor[gid] = o;
    }
    if (gid == 0) off[NN2] = boff[SCAN_NB];
}

__global__ void scatter2_kernel(const int* __restrict__ ei0, const int* __restrict__ ei1,
                                int* __restrict__ cursor,
                                unsigned short* __restrict__ csr16) {
    const int e = blockIdx.x * 256 + threadIdx.x;
    if (e >= NE2) return;
    const int g = e >= N_EDGES;
    const int* ei = g ? ei1 : ei0;
    const int e2 = e - g * N_EDGES;
    const int src = g * N_NODES + ei[e2];           // < 60000, fits u16
    const int dst = g * N_NODES + ei[N_EDGES + e2];
    const int slot = atomicAdd(&cursor[dst], 1);
    csr16[slot] = (unsigned short)src;
}

// ---------- aggregation (layers 1-2): in-loop w + fp8 gather + ELU, bf16 out ----------
// one wave per (node, head); L lanes per edge; es[src] is a broadcast load (L2-resident),
// ed[n] wave-uniform — no shfl in the loop (R6 lesson).
template <int HF>
__global__ void agg_fp8_kernel(const int* __restrict__ off,
                               const unsigned short* __restrict__ csr16,
                               const float* __restrict__ es, const float* __restrict__ ed,
                               const unsigned* __restrict__ zf8,
                               unsigned short* __restrict__ outz) {
    constexpr int Fo  = HF / HEADS;
    constexpr int L   = Fo / 4;
    constexpr int EPI = 64 / L;
    const int wid  = (blockIdx.x * blockDim.x + threadIdx.x) >> 6;
    const int lane = threadIdx.x & 63;
    if (wid >= NN2 * HEADS) return;
    const int n = wid / HEADS;
    const int h = wid - n * HEADS;
    const int s0  = off[n];
    const int deg = off[n + 1] - s0;
    const float edn = ed[n * HEADS + h];
    const int eo = lane / L;
    const int fp = lane - eo * L;

    float a0 = 0.f, a1 = 0.f, a2 = 0.f, a3 = 0.f, lsum = 0.f;
#pragma unroll 4
    for (int i = eo; i < deg; i += EPI) {
        const int src = (int)csr16[s0 + i];          // broadcast across L lanes
        float v = es[src * HEADS + h] + edn;         // L2-resident gather (es 1.4 MB)
        v = fmaxf(v, 0.2f * v);                      // leaky_relu
        const float ww = __expf(v);
        lsum += ww;
        const unsigned zz = zf8[(size_t)src * (HF / 4) + h * (Fo / 4) + fp];
        const f32x2 lo = __builtin_amdgcn_cvt_pk_f32_fp8((int)zz, false);
        const f32x2 hi = __builtin_amdgcn_cvt_pk_f32_fp8((int)zz, true);
        a0 = fmaf(ww, lo.x, a0);
        a1 = fmaf(ww, lo.y, a1);
        a2 = fmaf(ww, hi.x, a2);
        a3 = fmaf(ww, hi.y, a3);
    }
#pragma unroll
    for (int d = L; d < 64; d <<= 1) {
        a0 += __shfl_xor(a0, d);
        a1 += __shfl_xor(a1, d);
        a2 += __shfl_xor(a2, d);
        a3 += __shfl_xor(a3, d);
        lsum += __shfl_xor(lsum, d);
    }
    if (eo == 0) {
        const float inv = 1.f / (lsum + 1e-16f);
        float o0 = a0 * inv, o1 = a1 * inv, o2 = a2 * inv, o3 = a3 * inv;
        o0 = o0 > 0.f ? o0 : expm1f(o0);
        o1 = o1 > 0.f ? o1 : expm1f(o1);
        o2 = o2 > 0.f ? o2 : expm1f(o2);
        o3 = o3 > 0.f ? o3 : expm1f(o3);
        unsigned short* op = outz + (size_t)n * HF + h * Fo + 4 * fp;
        *(unsigned*)op       = (unsigned)f2bf(o0) | ((unsigned)f2bf(o1) << 16);
        *(unsigned*)(op + 2) = (unsigned)f2bf(o2) | ((unsigned)f2bf(o3) << 16);
    }
}

// ---------- layer-3 aggregation fused with sum pooling (hierarchical reduction) ----------
#define POOL_BPH 512
#define POOL_WPH (POOL_BPH * 4)   // waves per head = 2048
__global__ __launch_bounds__(256) void agg_pool_kernel(
        const int* __restrict__ off, const unsigned short* __restrict__ csr16,
        const float* __restrict__ es, const float* __restrict__ ed,
        const unsigned* __restrict__ zf8, float* __restrict__ pooled) {
    constexpr int HF = 384, Fo = 64, L = 16, EPI = 4;
    __shared__ float lds[128];   // [graph][64 feats] for this block's head
    const int h     = blockIdx.x % HEADS;           // fixed head per BLOCK
    const int bslot = blockIdx.x / HEADS;
    const int wavid = threadIdx.x >> 6;
    const int ws    = bslot * 4 + wavid;
    const int lane  = threadIdx.x & 63;
    const int eo = lane / L;
    const int fp = lane - eo * L;

    if (threadIdx.x < 128) lds[threadIdx.x] = 0.f;
    __syncthreads();

    float p0[4] = {0.f, 0.f, 0.f, 0.f};
    float p1[4] = {0.f, 0.f, 0.f, 0.f};
    for (int n = ws; n < NN2; n += POOL_WPH) {
        const int s0  = off[n];
        const int deg = off[n + 1] - s0;
        const float edn = ed[n * HEADS + h];
        float a0 = 0.f, a1 = 0.f, a2 = 0.f, a3 = 0.f, lsum = 0.f;
#pragma unroll 4
        for (int i = eo; i < deg; i += EPI) {
            const int src = (int)csr16[s0 + i];
            float v = es[src * HEADS + h] + edn;
            v = fmaxf(v, 0.2f * v);
            const float ww = __expf(v);
            lsum += ww;
            const unsigned zz = zf8[(size_t)src * (HF / 4) + h * (Fo / 4) + fp];
            const f32x2 lo = __builtin_amdgcn_cvt_pk_f32_fp8((int)zz, false);
            const f32x2 hi = __builtin_amdgcn_cvt_pk_f32_fp8((int)zz, true);
            a0 = fmaf(ww, lo.x, a0);
            a1 = fmaf(ww, lo.y, a1);
            a2 = fmaf(ww, hi.x, a2);
            a3 = fmaf(ww, hi.y, a3);
        }
#pragma unroll
        for (int d = L; d < 64; d <<= 1) {
            a0 += __shfl_xor(a0, d);
            a1 += __shfl_xor(a1, d);
            a2 += __shfl_xor(a2, d);
            a3 += __shfl_xor(a3, d);
            lsum += __shfl_xor(lsum, d);
        }
        if (eo == 0) {
            const float inv = 1.f / (lsum + 1e-16f);
            float o0 = a0 * inv, o1 = a1 * inv, o2 = a2 * inv, o3 = a3 * inv;
            o0 = o0 > 0.f ? o0 : expm1f(o0);
            o1 = o1 > 0.f ? o1 : expm1f(o1);
            o2 = o2 > 0.f ? o2 : expm1f(o2);
            o3 = o3 > 0.f ? o3 : expm1f(o3);
            if (n < N_NODES) { p0[0] += o0; p0[1] += o1; p0[2] += o2; p0[3] += o3; }
            else             { p1[0] += o0; p1[1] += o1; p1[2] += o2; p1[3] += o3; }
        }
    }
    if (eo == 0) {
#pragma unroll
        for (int j = 0; j < 4; ++j) {
            atomicAdd(&lds[4 * fp + j], p0[j]);
            atomicAdd(&lds[64 + 4 * fp + j], p1[j]);
        }
    }
    __syncthreads();
    if (threadIdx.x < 128) {
        const int g = threadIdx.x >> 6;
        const int f = threadIdx.x & 63;
        atomicAdd(&pooled[g * 384 + h * Fo + f], lds[threadIdx.x]);
    }
}

__global__ void zero_pooled_kernel(float* __restrict__ p) {
    const int i = blockIdx.x * 256 + threadIdx.x;
    if (i < 768) p[i] = 0.f;
}

__global__ void final_kernel(const float* __restrict__ pooled, const float* __restrict__ Wd,
                             const float* __restrict__ bd, float* __restrict__ outp) {
    __shared__ float s_ss[256], s_dot[256];
    const int t = threadIdx.x;
    float ss = 0.f, dot = 0.f;
    for (int c = t; c < 768; c += 256) {
        const float v = pooled[c];
        ss  = fmaf(v, v, ss);
        dot = fmaf(v, Wd[c], dot);
    }
    s_ss[t] = ss; s_dot[t] = dot;
    __syncthreads();
    for (int off = 128; off > 0; off >>= 1) {
        if (t < off) { s_ss[t] += s_ss[t + off]; s_dot[t] += s_dot[t + off]; }
        __syncthreads();
    }
    if (t == 0) {
        const float norm = fmaxf(sqrtf(s_ss[0]), 1e-12f);
        outp[0] = s_dot[0] / norm + bd[0];
    }
}

extern "C" void kernel_launch(void* const* d_in, const int* in_sizes, int n_in,
                              void* d_out, int out_size, void* d_ws, size_t ws_size,
                              hipStream_t stream) {
    const float* x_int = (const float*)d_in[0];
    const float* x_nh  = (const float*)d_in[1];
    const int*   ei_int = (const int*)d_in[2];
    const int*   ei_nh  = (const int*)d_in[3];
    const float* W1  = (const float*)d_in[4];
    const float* a1s = (const float*)d_in[5];
    const float* a1d = (const float*)d_in[6];
    const float* W2  = (const float*)d_in[7];
    const float* a2s = (const float*)d_in[8];
    const float* a2d = (const float*)d_in[9];
    const float* W3  = (const float*)d_in[10];
    const float* a3s = (const float*)d_in[11];
    const float* a3d = (const float*)d_in[12];
    const float* Wd  = (const float*)d_in[13];
    const float* bd  = (const float*)d_in[14];
    float* out = (float*)d_out;

    // workspace layout (zbuf 256B-aligned at base; all offsets keep 16B alignment)
    unsigned short* zbuf  = (unsigned short*)d_ws;                 // NN2*384 bf16
    unsigned short* hbf_a = zbuf  + (size_t)NN2 * 384;             // NN2*96
    unsigned short* hbf_b = hbf_a + (size_t)NN2 * 96;              // NN2*192
    unsigned short* wt2   = hbf_b + (size_t)NN2 * 192;             // 192*96
    unsigned short* wt3   = wt2   + (size_t)96 * 192;              // 384*192
    unsigned* zf8 = (unsigned*)(wt3 + (size_t)192 * 384);          // NN2*96 dwords (fp8)
    float* es    = (float*)(zf8 + (size_t)NN2 * 96);               // NN2*H
    float* ed    = es + (size_t)NN2 * HEADS;                       // NN2*H
    float* pooled = ed + (size_t)NN2 * HEADS;                      // 768
    int* cnt     = (int*)(pooled + 768);                           // NN2
    int* part    = cnt + NN2;                                      // SCAN_NB*1024
    int* bsum    = part + SCAN_NB * 1024;                          // SCAN_NB
    int* boff    = bsum + SCAN_NB;                                 // SCAN_NB+1
    int* off     = boff + SCAN_NB + 1;                             // NN2+1
    int* cursor  = off + NN2 + 1;                                  // NN2
    unsigned short* csr16 = (unsigned short*)(cursor + NN2);       // NE2 u16

    zero_pooled_kernel<<<3, 256, 0, stream>>>(pooled);
    convert_wt_kernel<<<(96 * 192 + 255) / 256, 256, 0, stream>>>(W2, wt2, 96, 192);
    convert_wt_kernel<<<(192 * 384 + 255) / 256, 256, 0, stream>>>(W3, wt3, 192, 384);

    // batched CSR over both graphs
    zero_int_kernel<<<(NN2 + 255) / 256, 256, 0, stream>>>(cnt, NN2);
    hist2_kernel<<<(NE2 + 255) / 256, 256, 0, stream>>>(ei_int, ei_nh, cnt);
    scan1_kernel<<<SCAN_NB, 1024, 0, stream>>>(cnt, part, bsum);
    scan2_kernel<<<1, 64, 0, stream>>>(bsum, boff);
    scan3_kernel<<<SCAN_NB, 1024, 0, stream>>>(part, boff, off, cursor);
    scatter2_kernel<<<(NE2 + 255) / 256, 256, 0, stream>>>(ei_int, ei_nh, cursor, csr16);

    const int mfma_blocks = (NN2 / 16 + 3) / 4;
    const int agg_blocks  = (NN2 * HEADS + 3) / 4;   // 1 wave per (node, head)
    const int prep_blocks = (NN2 * HEADS + 255) / 256;

    // layer 1
    gemm1_kernel<11, 96, 16><<<dim3(NN2 / 16, 2), 64, 0, stream>>>(x_int, x_nh, W1, zbuf);
    prep_fp8_kernel<96><<<prep_blocks, 256, 0, stream>>>(zbuf, a1s, a1d, es, ed, zf8);
    agg_fp8_kernel<96><<<agg_blocks, 256, 0, stream>>>(off, csr16, es, ed, zf8, hbf_a);
    // layer 2
    gemm_mfma_kernel<96, 192><<<mfma_blocks, 256, 0, stream>>>(hbf_a, wt2, zbuf);
    prep_fp8_kernel<192><<<prep_blocks, 256, 0, stream>>>(zbuf, a2s, a2d, es, ed, zf8);
    agg_fp8_kernel<192><<<agg_blocks, 256, 0, stream>>>(off, csr16, es, ed, zf8, hbf_b);
    // layer 3 (+ fused pooling, hierarchical reduction)
    gemm_mfma_kernel<192, 384><<<mfma_blocks, 256, 0, stream>>>(hbf_b, wt3, zbuf);
    prep_fp8_kernel<384><<<prep_blocks, 256, 0, stream>>>(zbuf, a3s, a3d, es, ed, zf8);
    agg_pool_kernel<<<HEADS * POOL_BPH, 256, 0, stream>>>(off, csr16, es, ed, zf8, pooled);

    final_kernel<<<1, 256, 0, stream>>>(pooled, Wd, bd, out);
}

// Round 12
// 756.948 us; speedup vs baseline: 1.0865x; 1.0309x over previous
//
#include <hip/hip_runtime.h>
#include <math.h>

#define N_NODES 30000
#define N_EDGES 480000
#define HEADS   6
#define NN2 (2 * N_NODES)
#define NE2 (2 * N_EDGES)

typedef __attribute__((ext_vector_type(8))) short bf16x8;
typedef __attribute__((ext_vector_type(4))) float f32x4;
typedef __attribute__((ext_vector_type(2))) float f32x2;

// ---------- bf16 helpers ----------
__device__ __forceinline__ unsigned short f2bf(float f) {
    unsigned u = __float_as_uint(f);
    u += 0x7fffu + ((u >> 16) & 1u);   // RNE
    return (unsigned short)(u >> 16);
}
__device__ __forceinline__ float bf_lo(unsigned p) { return __uint_as_float(p << 16); }
__device__ __forceinline__ float bf_hi(unsigned p) { return __uint_as_float(p & 0xffff0000u); }

// ---------- layer-1 GEMM (K=11): VALU, both graphs batched ----------
template <int K, int HF, int TM>
__global__ void gemm1_kernel(const float* __restrict__ x0, const float* __restrict__ x1,
                             const float* __restrict__ W, unsigned short* __restrict__ z) {
    __shared__ float hs[TM * K];
    const int m0 = blockIdx.x * TM;
    const float* h = (m0 < N_NODES) ? (x0 + (size_t)m0 * K)
                                    : (x1 + (size_t)(m0 - N_NODES) * K);
    const int j = blockIdx.y * 64 + threadIdx.x;
    for (int idx = threadIdx.x; idx < TM * K; idx += 64) hs[idx] = h[idx];
    __syncthreads();
    if (j >= HF) return;
    float acc[TM];
#pragma unroll
    for (int m = 0; m < TM; ++m) acc[m] = 0.f;
    for (int k = 0; k < K; ++k) {
        float w = W[k * HF + j];
#pragma unroll
        for (int m = 0; m < TM; ++m) acc[m] = fmaf(hs[m * K + k], w, acc[m]);
    }
#pragma unroll
    for (int m = 0; m < TM; ++m) z[(size_t)(m0 + m) * HF + j] = f2bf(acc[m]);
}

// ---------- W -> Wt (transposed, bf16) ----------
__global__ void convert_wt_kernel(const float* __restrict__ W, unsigned short* __restrict__ Wt,
                                  int K, int HF) {
    const int idx = blockIdx.x * 256 + threadIdx.x;
    if (idx >= K * HF) return;
    const int k = idx / HF;
    const int n = idx - k * HF;
    Wt[n * K + k] = f2bf(W[idx]);
}

// ---------- MFMA GEMM over 2N rows ----------
template <int K, int HF>
__global__ __launch_bounds__(256) void gemm_mfma_kernel(
        const unsigned short* __restrict__ hbf, const unsigned short* __restrict__ Wt,
        unsigned short* __restrict__ z) {
    constexpr int KSTEPS = K / 32;
    const int wid = blockIdx.x * 4 + (threadIdx.x >> 6);
    if (wid >= NN2 / 16) return;
    const int lane = threadIdx.x & 63;
    const int r16  = lane & 15;
    const int quad = lane >> 4;
    const int m0 = wid * 16;

    bf16x8 afrag[KSTEPS];
    const unsigned short* ap = hbf + (size_t)(m0 + r16) * K + quad * 8;
#pragma unroll
    for (int i = 0; i < KSTEPS; ++i) afrag[i] = *(const bf16x8*)(ap + i * 32);

    const unsigned short* bp = Wt + (size_t)r16 * K + quad * 8;
    for (int t = 0; t < HF / 16; ++t) {
        f32x4 acc = {0.f, 0.f, 0.f, 0.f};
        const unsigned short* bpt = bp + (size_t)t * 16 * K;
#pragma unroll
        for (int i = 0; i < KSTEPS; ++i) {
            const bf16x8 bfrag = *(const bf16x8*)(bpt + i * 32);
            acc = __builtin_amdgcn_mfma_f32_16x16x32_bf16(afrag[i], bfrag, acc, 0, 0, 0);
        }
        // C/D layout: col = r16 (n), row = quad*4 + reg (m)
        unsigned short* zp = z + (size_t)(m0 + quad * 4) * HF + t * 16 + r16;
#pragma unroll
        for (int r = 0; r < 4; ++r) zp[(size_t)r * HF] = f2bf(acc[r]);
    }
}

// ---------- prep: es/ed (transposed [h][n]) from bf16 z + emit packed fp8 z copy ------
template <int HF>
__global__ void prep_fp8_kernel(const unsigned short* __restrict__ z,
                                const float* __restrict__ a_s, const float* __restrict__ a_d,
                                float* __restrict__ es_t, float* __restrict__ ed_t,
                                unsigned* __restrict__ zf8) {
    constexpr int Fo = HF / HEADS;
    const int idx = blockIdx.x * 256 + threadIdx.x;
    if (idx >= NN2 * HEADS) return;
    const int n = idx / HEADS;
    const int h = idx - n * HEADS;
    const unsigned* zp = (const unsigned*)(z + (size_t)n * HF + h * Fo);
    unsigned* qp = zf8 + ((size_t)n * (HF / 4) + h * (Fo / 4));
    const float* as = a_s + h * Fo;
    const float* ad = a_d + h * Fo;
    float s = 0.f, d = 0.f;
#pragma unroll 4
    for (int q = 0; q < Fo / 4; ++q) {
        const unsigned za = zp[2 * q], zb = zp[2 * q + 1];
        const float f0 = bf_lo(za), f1 = bf_hi(za), f2 = bf_lo(zb), f3 = bf_hi(zb);
        s = fmaf(f0, as[4 * q], s);
        s = fmaf(f1, as[4 * q + 1], s);
        s = fmaf(f2, as[4 * q + 2], s);
        s = fmaf(f3, as[4 * q + 3], s);
        d = fmaf(f0, ad[4 * q], d);
        d = fmaf(f1, ad[4 * q + 1], d);
        d = fmaf(f2, ad[4 * q + 2], d);
        d = fmaf(f3, ad[4 * q + 3], d);
        int u = __builtin_amdgcn_cvt_pk_fp8_f32(f0, f1, 0, false);
        u = __builtin_amdgcn_cvt_pk_fp8_f32(f2, f3, u, true);
        qp[q] = (unsigned)u;
    }
    es_t[(size_t)h * NN2 + n] = s;   // transposed: per-head contiguous 240 KB slice
    ed_t[(size_t)h * NN2 + n] = d;
}

// ---------- CSR build (both graphs, global node ids; src stored as u16) ----------
__global__ void zero_int_kernel(int* __restrict__ p, int n) {
    const int i = blockIdx.x * 256 + threadIdx.x;
    if (i < n) p[i] = 0;
}

__global__ void hist2_kernel(const int* __restrict__ ei0, const int* __restrict__ ei1,
                             int* __restrict__ cnt) {
    const int e = blockIdx.x * 256 + threadIdx.x;
    if (e >= NE2) return;
    const int g = e >= N_EDGES;
    const int* ei = g ? ei1 : ei0;
    const int e2 = e - g * N_EDGES;
    atomicAdd(&cnt[g * N_NODES + ei[N_EDGES + e2]], 1);
}

#define SCAN_NB ((NN2 + 1023) / 1024)
__global__ void scan1_kernel(const int* __restrict__ cnt, int* __restrict__ part,
                             int* __restrict__ bsum) {
    __shared__ int s[1024];
    const int t = threadIdx.x;
    const int gid = blockIdx.x * 1024 + t;
    const int v = (gid < NN2) ? cnt[gid] : 0;
    s[t] = v;
    __syncthreads();
    for (int d = 1; d < 1024; d <<= 1) {
        int x = (t >= d) ? s[t - d] : 0;
        __syncthreads();
        s[t] += x;
        __syncthreads();
    }
    part[gid] = s[t] - v;
    if (t == 1023) bsum[blockIdx.x] = s[1023];
}

__global__ void scan2_kernel(int* __restrict__ bsum, int* __restrict__ boff) {
    if (threadIdx.x == 0) {
        int a = 0;
        for (int i = 0; i < SCAN_NB; ++i) { boff[i] = a; a += bsum[i]; }
        boff[SCAN_NB] = a;
    }
}

__global__ void scan3_kernel(const int* __restrict__ part, const int* __restrict__ boff,
                             int* __restrict__ off, int* __restrict__ cursor) {
    const int gid = blockIdx.x * 1024 + threadIdx.x;
    if (gid < NN2) {
        const int o = part[gid] + boff[gid >> 10];
        off[gid] = o;
        cursor[gid] = o;
    }
    if (gid == 0) off[NN2] = boff[SCAN_NB];
}

__global__ void scatter2_kernel(const int* __restrict__ ei0, const int* __restrict__ ei1,
                                int* __restrict__ cursor,
                                unsigned short* __restrict__ csr16) {
    const int e = blockIdx.x * 256 + threadIdx.x;
    if (e >= NE2) return;
    const int g = e >= N_EDGES;
    const int* ei = g ? ei1 : ei0;
    const int e2 = e - g * N_EDGES;
    const int src = g * N_NODES + ei[e2];           // < 60000, fits u16
    const int dst = g * N_NODES + ei[N_EDGES + e2];
    const int slot = atomicAdd(&cursor[dst], 1);
    csr16[slot] = (unsigned short)src;
}

// ---------- XCD-affine head decode: blocks with b%8==r<6 carry head r ----------
// (blockIdx -> XCD is round-robin %8 heuristic; wrong mapping costs speed only)
__device__ __forceinline__ void head_swizzle(int b, int per_head_main, int per_head_fill,
                                             int& h, int& idx) {
    const int r = b & 7, g = b >> 3;
    if (r < 6) { h = r; idx = g; }
    else {
        h = g % 6;
        idx = per_head_main + (r - 6) * per_head_fill + g / 6;
    }
}

// ---------- aggregation (layers 1-2): in-loop w + fp8 gather + ELU, bf16 out ----------
// head-major blocks (4 nodes/block, one head) with XCD-affine swizzle
template <int HF>
__global__ void agg_fp8_kernel(const int* __restrict__ off,
                               const unsigned short* __restrict__ csr16,
                               const float* __restrict__ es_t, const float* __restrict__ ed_t,
                               const unsigned* __restrict__ zf8,
                               unsigned short* __restrict__ outz) {
    constexpr int Fo  = HF / HEADS;
    constexpr int L   = Fo / 4;
    constexpr int EPI = 64 / L;
    int h, idx;
    head_swizzle(blockIdx.x, (NN2 / 4) * 6 / 8, (NN2 / 4) / 8 / 2 * 2 == 0 ? 0 : 0, h, idx);
    // per_head_main = blocks from XCDs 0-5 per head = (NN2*6/4)/8 = 11250
    // per_head_fill = remaining per head per XCD = 1875
    {
        const int r = blockIdx.x & 7, g = blockIdx.x >> 3;
        if (r < 6) { h = r; idx = g; }
        else { h = g % 6; idx = 11250 + (r - 6) * 1875 + g / 6; }
    }
    const int n = idx * 4 + (threadIdx.x >> 6);
    const int lane = threadIdx.x & 63;
    const int s0  = off[n];
    const int deg = off[n + 1] - s0;
    const float edn = ed_t[(size_t)h * NN2 + n];
    const float* esh = es_t + (size_t)h * NN2;
    const int eo = lane / L;
    const int fp = lane - eo * L;

    float a0 = 0.f, a1 = 0.f, a2 = 0.f, a3 = 0.f, lsum = 0.f;
#pragma unroll 4
    for (int i = eo; i < deg; i += EPI) {
        const int src = (int)csr16[s0 + i];          // broadcast across L lanes
        float v = esh[src] + edn;                    // per-head 240KB slice (L2-resident)
        v = fmaxf(v, 0.2f * v);                      // leaky_relu
        const float ww = __expf(v);
        lsum += ww;
        const unsigned zz = zf8[(size_t)src * (HF / 4) + h * (Fo / 4) + fp];
        const f32x2 lo = __builtin_amdgcn_cvt_pk_f32_fp8((int)zz, false);
        const f32x2 hi = __builtin_amdgcn_cvt_pk_f32_fp8((int)zz, true);
        a0 = fmaf(ww, lo.x, a0);
        a1 = fmaf(ww, lo.y, a1);
        a2 = fmaf(ww, hi.x, a2);
        a3 = fmaf(ww, hi.y, a3);
    }
#pragma unroll
    for (int d = L; d < 64; d <<= 1) {
        a0 += __shfl_xor(a0, d);
        a1 += __shfl_xor(a1, d);
        a2 += __shfl_xor(a2, d);
        a3 += __shfl_xor(a3, d);
        lsum += __shfl_xor(lsum, d);
    }
    if (eo == 0) {
        const float inv = 1.f / (lsum + 1e-16f);
        float o0 = a0 * inv, o1 = a1 * inv, o2 = a2 * inv, o3 = a3 * inv;
        o0 = o0 > 0.f ? o0 : expm1f(o0);
        o1 = o1 > 0.f ? o1 : expm1f(o1);
        o2 = o2 > 0.f ? o2 : expm1f(o2);
        o3 = o3 > 0.f ? o3 : expm1f(o3);
        unsigned short* op = outz + (size_t)n * HF + h * Fo + 4 * fp;
        *(unsigned*)op       = (unsigned)f2bf(o0) | ((unsigned)f2bf(o1) << 16);
        *(unsigned*)(op + 2) = (unsigned)f2bf(o2) | ((unsigned)f2bf(o3) << 16);
    }
}

// ---------- layer-3 aggregation fused with sum pooling (hierarchical reduction) ----------
// XCD-affine head swizzle: 3072 blocks, 512 per head
#define POOL_BLOCKS 3072
#define POOL_WPH 2048   // waves per head = 512 blocks * 4
__global__ __launch_bounds__(256) void agg_pool_kernel(
        const int* __restrict__ off, const unsigned short* __restrict__ csr16,
        const float* __restrict__ es_t, const float* __restrict__ ed_t,
        const unsigned* __restrict__ zf8, float* __restrict__ pooled) {
    constexpr int HF = 384, Fo = 64, L = 16, EPI = 4;
    __shared__ float lds[128];   // [graph][64 feats] for this block's head
    int h, slot;
    {
        const int r = blockIdx.x & 7, g = blockIdx.x >> 3;   // g in [0,384)
        if (r < 6) { h = r; slot = g; }
        else { h = g % 6; slot = 384 + (r - 6) * 64 + g / 6; }
    }
    const int wavid = threadIdx.x >> 6;
    const int ws    = slot * 4 + wavid;
    const int lane  = threadIdx.x & 63;
    const int eo = lane / L;
    const int fp = lane - eo * L;
    const float* esh = es_t + (size_t)h * NN2;
    const float* edh = ed_t + (size_t)h * NN2;

    if (threadIdx.x < 128) lds[threadIdx.x] = 0.f;
    __syncthreads();

    float p0[4] = {0.f, 0.f, 0.f, 0.f};
    float p1[4] = {0.f, 0.f, 0.f, 0.f};
    for (int n = ws; n < NN2; n += POOL_WPH) {
        const int s0  = off[n];
        const int deg = off[n + 1] - s0;
        const float edn = edh[n];
        float a0 = 0.f, a1 = 0.f, a2 = 0.f, a3 = 0.f, lsum = 0.f;
#pragma unroll 4
        for (int i = eo; i < deg; i += EPI) {
            const int src = (int)csr16[s0 + i];
            float v = esh[src] + edn;
            v = fmaxf(v, 0.2f * v);
            const float ww = __expf(v);
            lsum += ww;
            const unsigned zz = zf8[(size_t)src * (HF / 4) + h * (Fo / 4) + fp];
            const f32x2 lo = __builtin_amdgcn_cvt_pk_f32_fp8((int)zz, false);
            const f32x2 hi = __builtin_amdgcn_cvt_pk_f32_fp8((int)zz, true);
            a0 = fmaf(ww, lo.x, a0);
            a1 = fmaf(ww, lo.y, a1);
            a2 = fmaf(ww, hi.x, a2);
            a3 = fmaf(ww, hi.y, a3);
        }
#pragma unroll
        for (int d = L; d < 64; d <<= 1) {
            a0 += __shfl_xor(a0, d);
            a1 += __shfl_xor(a1, d);
            a2 += __shfl_xor(a2, d);
            a3 += __shfl_xor(a3, d);
            lsum += __shfl_xor(lsum, d);
        }
        if (eo == 0) {
            const float inv = 1.f / (lsum + 1e-16f);
            float o0 = a0 * inv, o1 = a1 * inv, o2 = a2 * inv, o3 = a3 * inv;
            o0 = o0 > 0.f ? o0 : expm1f(o0);
            o1 = o1 > 0.f ? o1 : expm1f(o1);
            o2 = o2 > 0.f ? o2 : expm1f(o2);
            o3 = o3 > 0.f ? o3 : expm1f(o3);
            if (n < N_NODES) { p0[0] += o0; p0[1] += o1; p0[2] += o2; p0[3] += o3; }
            else             { p1[0] += o0; p1[1] += o1; p1[2] += o2; p1[3] += o3; }
        }
    }
    if (eo == 0) {
#pragma unroll
        for (int j = 0; j < 4; ++j) {
            atomicAdd(&lds[4 * fp + j], p0[j]);
            atomicAdd(&lds[64 + 4 * fp + j], p1[j]);
        }
    }
    __syncthreads();
    if (threadIdx.x < 128) {
        const int g = threadIdx.x >> 6;
        const int f = threadIdx.x & 63;
        atomicAdd(&pooled[g * 384 + h * Fo + f], lds[threadIdx.x]);
    }
}

__global__ void zero_pooled_kernel(float* __restrict__ p) {
    const int i = blockIdx.x * 256 + threadIdx.x;
    if (i < 768) p[i] = 0.f;
}

__global__ void final_kernel(const float* __restrict__ pooled, const float* __restrict__ Wd,
                             const float* __restrict__ bd, float* __restrict__ outp) {
    __shared__ float s_ss[256], s_dot[256];
    const int t = threadIdx.x;
    float ss = 0.f, dot = 0.f;
    for (int c = t; c < 768; c += 256) {
        const float v = pooled[c];
        ss  = fmaf(v, v, ss);
        dot = fmaf(v, Wd[c], dot);
    }
    s_ss[t] = ss; s_dot[t] = dot;
    __syncthreads();
    for (int off = 128; off > 0; off >>= 1) {
        if (t < off) { s_ss[t] += s_ss[t + off]; s_dot[t] += s_dot[t + off]; }
        __syncthreads();
    }
    if (t == 0) {
        const float norm = fmaxf(sqrtf(s_ss[0]), 1e-12f);
        outp[0] = s_dot[0] / norm + bd[0];
    }
}

extern "C" void kernel_launch(void* const* d_in, const int* in_sizes, int n_in,
                              void* d_out, int out_size, void* d_ws, size_t ws_size,
                              hipStream_t stream) {
    const float* x_int = (const float*)d_in[0];
    const float* x_nh  = (const float*)d_in[1];
    const int*   ei_int = (const int*)d_in[2];
    const int*   ei_nh  = (const int*)d_in[3];
    const float* W1  = (const float*)d_in[4];
    const float* a1s = (const float*)d_in[5];
    const float* a1d = (const float*)d_in[6];
    const float* W2  = (const float*)d_in[7];
    const float* a2s = (const float*)d_in[8];
    const float* a2d = (const float*)d_in[9];
    const float* W3  = (const float*)d_in[10];
    const float* a3s = (const float*)d_in[11];
    const float* a3d = (const float*)d_in[12];
    const float* Wd  = (const float*)d_in[13];
    const float* bd  = (const float*)d_in[14];
    float* out = (float*)d_out;

    // workspace layout (zbuf 256B-aligned at base; all offsets keep 16B alignment)
    unsigned short* zbuf  = (unsigned short*)d_ws;                 // NN2*384 bf16
    unsigned short* hbf_a = zbuf  + (size_t)NN2 * 384;             // NN2*96
    unsigned short* hbf_b = hbf_a + (size_t)NN2 * 96;              // NN2*192
    unsigned short* wt2   = hbf_b + (size_t)NN2 * 192;             // 192*96
    unsigned short* wt3   = wt2   + (size_t)96 * 192;              // 384*192
    unsigned* zf8 = (unsigned*)(wt3 + (size_t)192 * 384);          // NN2*96 dwords (fp8)
    float* es_t  = (float*)(zf8 + (size_t)NN2 * 96);               // H*NN2 (transposed)
    float* ed_t  = es_t + (size_t)HEADS * NN2;                     // H*NN2
    float* pooled = ed_t + (size_t)HEADS * NN2;                    // 768
    int* cnt     = (int*)(pooled + 768);                           // NN2
    int* part    = cnt + NN2;                                      // SCAN_NB*1024
    int* bsum    = part + SCAN_NB * 1024;                          // SCAN_NB
    int* boff    = bsum + SCAN_NB;                                 // SCAN_NB+1
    int* off     = boff + SCAN_NB + 1;                             // NN2+1
    int* cursor  = off + NN2 + 1;                                  // NN2
    unsigned short* csr16 = (unsigned short*)(cursor + NN2);       // NE2 u16

    zero_pooled_kernel<<<3, 256, 0, stream>>>(pooled);
    convert_wt_kernel<<<(96 * 192 + 255) / 256, 256, 0, stream>>>(W2, wt2, 96, 192);
    convert_wt_kernel<<<(192 * 384 + 255) / 256, 256, 0, stream>>>(W3, wt3, 192, 384);

    // batched CSR over both graphs
    zero_int_kernel<<<(NN2 + 255) / 256, 256, 0, stream>>>(cnt, NN2);
    hist2_kernel<<<(NE2 + 255) / 256, 256, 0, stream>>>(ei_int, ei_nh, cnt);
    scan1_kernel<<<SCAN_NB, 1024, 0, stream>>>(cnt, part, bsum);
    scan2_kernel<<<1, 64, 0, stream>>>(bsum, boff);
    scan3_kernel<<<SCAN_NB, 1024, 0, stream>>>(part, boff, off, cursor);
    scatter2_kernel<<<(NE2 + 255) / 256, 256, 0, stream>>>(ei_int, ei_nh, cursor, csr16);

    const int mfma_blocks = (NN2 / 16 + 3) / 4;
    const int agg_blocks  = NN2 * HEADS / 4;         // 90000, head-major swizzled
    const int prep_blocks = (NN2 * HEADS + 255) / 256;

    // layer 1
    gemm1_kernel<11, 96, 16><<<dim3(NN2 / 16, 2), 64, 0, stream>>>(x_int, x_nh, W1, zbuf);
    prep_fp8_kernel<96><<<prep_blocks, 256, 0, stream>>>(zbuf, a1s, a1d, es_t, ed_t, zf8);
    agg_fp8_kernel<96><<<agg_blocks, 256, 0, stream>>>(off, csr16, es_t, ed_t, zf8, hbf_a);
    // layer 2
    gemm_mfma_kernel<96, 192><<<mfma_blocks, 256, 0, stream>>>(hbf_a, wt2, zbuf);
    prep_fp8_kernel<192><<<prep_blocks, 256, 0, stream>>>(zbuf, a2s, a2d, es_t, ed_t, zf8);
    agg_fp8_kernel<192><<<agg_blocks, 256, 0, stream>>>(off, csr16, es_t, ed_t, zf8, hbf_b);
    // layer 3 (+ fused pooling, hierarchical reduction)
    gemm_mfma_kernel<192, 384><<<mfma_blocks, 256, 0, stream>>>(hbf_b, wt3, zbuf);
    prep_fp8_kernel<384><<<prep_blocks, 256, 0, stream>>>(zbuf, a3s, a3d, es_t, ed_t, zf8);
    agg_pool_kernel<<<POOL_BLOCKS, 256, 0, stream>>>(off, csr16, es_t, ed_t, zf8, pooled);

    final_kernel<<<1, 256, 0, stream>>>(pooled, Wd, bd, out);
}